// Round 5
// baseline (201.104 us; speedup 1.0000x reference)
//
#include <hip/hip_runtime.h>
#include <math.h>

#define NRES 22
#define RPB  64   // residues per 256-thread block

// LDS dword offsets (total 8192 dwords = 32 KB exactly)
#define L_FR   0      // frames: 64 residues * 98 (8 frames * 12 floats, pad 2)
#define L_O0   6272   // o0 tile: 64*17
#define L_O1   7360   // o1 tile: 64*9
#define L_POS  7936   // pos tile: 64*3
#define L_META 8128   // 64 ints: cmb | (rt<<16)
#define L_TOT  8192

// Select fr[d] (d in 0..7) into P via a 3-level cndmask tree (registers only).
__device__ __forceinline__ void sel8(const float (&fr)[8][12], int d, float (&P)[12]) {
    const bool b0 = (d & 1) != 0;
    const bool b1 = (d & 2) != 0;
    const bool b2 = (d & 4) != 0;
#pragma unroll
    for (int k = 0; k < 12; ++k) {
        float a01 = b0 ? fr[1][k] : fr[0][k];
        float a23 = b0 ? fr[3][k] : fr[2][k];
        float a45 = b0 ? fr[5][k] : fr[4][k];
        float a67 = b0 ? fr[7][k] : fr[6][k];
        float b03 = b1 ? a23 : a01;
        float b47 = b1 ? a67 : a45;
        P[k] = b2 ? b47 : b03;
    }
}

extern "C" __global__ __launch_bounds__(256)
void model_kernel(const float* __restrict__ o0,     // (N,17)
                  const float* __restrict__ o1,     // (N,3,3)
                  const float* __restrict__ pos,    // (N,3)
                  const int*   __restrict__ ssArr,  // (N,)
                  const int*   __restrict__ rtArr,  // (N,)
                  const float* __restrict__ rigT,   // (3,22,8,4,3)
                  const float* __restrict__ rigG,   // (3,22,24,3)
                  const int*   __restrict__ tdepArr,// (22,8)
                  const int*   __restrict__ rdepArr,// (22,24)
                  float* __restrict__ outR,         // (N,24,3)
                  float* __restrict__ outF,         // (N,4,3)
                  int N)
{
    __shared__ float lds[L_TOT];
    int* ilds = (int*)lds;

    const int tid = threadIdx.x;
    const int R0  = blockIdx.x * RPB;
    const int cnt = min(RPB, N - R0);

    // ---------------- Phase A: coalesced staging ----------------
    if (cnt == RPB) {
        const float4* s0v = (const float4*)(o0 + (size_t)R0 * 17);   // 272 float4
        float4* d0v = (float4*)(lds + L_O0);
        d0v[tid & 255] = s0v[tid & 255];                              // tid<256 always
        if (tid < 16) d0v[256 + tid] = s0v[256 + tid];
        if (tid < 144) {                                              // o1: 144 float4
            ((float4*)(lds + L_O1))[tid] = ((const float4*)(o1 + (size_t)R0 * 9))[tid];
        }
        if (tid < 48) {                                               // pos: 48 float4
            ((float4*)(lds + L_POS))[tid] = ((const float4*)(pos + (size_t)R0 * 3))[tid];
        }
    } else {
        for (int i = tid; i < cnt * 17; i += 256) lds[L_O0 + i]  = o0[(size_t)R0 * 17 + i];
        for (int i = tid; i < cnt * 9;  i += 256) lds[L_O1 + i]  = o1[(size_t)R0 * 9 + i];
        for (int i = tid; i < cnt * 3;  i += 256) lds[L_POS + i] = pos[(size_t)R0 * 3 + i];
    }
    if (tid < cnt) {
        int s = ssArr[R0 + tid];
        int r = rtArr[R0 + tid];
        ilds[L_META + tid] = (s * NRES + r) | (r << 16);
    }
    __syncthreads();

    // ---------------- Phase B: chain on wave 0 (1 lane = 1 residue) --------
    if (tid < RPB && tid < cnt) {
        const int l = tid;
        const int meta = ilds[L_META + l];
        const int cmb  = meta & 0xFFFF;
        const int rtv  = meta >> 16;

        // torsion cos/sin from LDS (stride 17: conflict-free)
        float c[7], sn[7];
        const float* myo0 = lds + L_O0 + l * 17;
#pragma unroll
        for (int t = 0; t < 7; ++t) {
            float cr = myo0[2 * t], sr = myo0[2 * t + 1];
            float inv = rsqrtf(fmaxf(cr * cr + sr * sr, 1e-12f));
            c[t]  = cr * inv;
            sn[t] = sr * inv;
        }

        // backbone frame (Gram-Schmidt) from LDS
        const float* o1p = lds + L_O1 + l * 9;
        const float* pp  = lds + L_POS + l * 3;
        float r0x = o1p[0], r0y = o1p[1], r0z = o1p[2];
        float v1x = o1p[3], v1y = o1p[4], v1z = o1p[5];
        float t2x = o1p[6], t2y = o1p[7], t2z = o1p[8];
        float inv0 = rsqrtf(fmaxf(r0x * r0x + r0y * r0y + r0z * r0z, 1e-12f));
        float e0x = r0x * inv0, e0y = r0y * inv0, e0z = r0z * inv0;
        float d01 = e0x * v1x + e0y * v1y + e0z * v1z;
        float u1x = v1x - e0x * d01, u1y = v1y - e0y * d01, u1z = v1z - e0z * d01;
        float inv1 = rsqrtf(fmaxf(u1x * u1x + u1y * u1y + u1z * u1z, 1e-12f));
        float e1x = u1x * inv1, e1y = u1y * inv1, e1z = u1z * inv1;
        float e2x = e0y * e1z - e0z * e1y;
        float e2y = e0z * e1x - e0x * e1z;
        float e2z = e0x * e1y - e0y * e1x;
        float btx = 0.1f * t2x + pp[0];
        float bty = 0.1f * t2y + pp[1];
        float btz = 0.1f * t2z + pp[2];

        const float4* T4 = (const float4*)rigT + (size_t)cmb * 24;
        float fr[8][12];

        {   // frame 0 = combine(T0, [rot(cols e0,e1,e2); bt])
            float4 q0 = T4[0], q1 = T4[1], q2 = T4[2];
            float T0[12] = {q0.x, q0.y, q0.z, q0.w, q1.x, q1.y, q1.z, q1.w,
                            q2.x, q2.y, q2.z, q2.w};
#pragma unroll
            for (int i = 0; i < 3; ++i) {
                float a = T0[i * 3 + 0], b = T0[i * 3 + 1], d = T0[i * 3 + 2];
                fr[0][i * 3 + 0] = a * e0x + b * e0y + d * e0z;
                fr[0][i * 3 + 1] = a * e1x + b * e1y + d * e1z;
                fr[0][i * 3 + 2] = a * e2x + b * e2y + d * e2z;
                fr[0][9 + i]     = a * btx + b * bty + d * btz + T0[9 + i];
            }
        }
#pragma unroll
        for (int f = 1; f < 8; ++f) {   // combine(Tf, rotX(c,s))
            float4 q0 = T4[f * 3 + 0], q1 = T4[f * 3 + 1], q2 = T4[f * 3 + 2];
            float Tf[12] = {q0.x, q0.y, q0.z, q0.w, q1.x, q1.y, q1.z, q1.w,
                            q2.x, q2.y, q2.z, q2.w};
            float cc = c[f - 1], ssn = sn[f - 1];
#pragma unroll
            for (int i = 0; i < 3; ++i) {
                float m1 = Tf[i * 3 + 1], m2 = Tf[i * 3 + 2];
                fr[f][i * 3 + 0] = Tf[i * 3 + 0];
                fr[f][i * 3 + 1] = m1 * cc + m2 * ssn;
                fr[f][i * 3 + 2] = m2 * cc - m1 * ssn;
                fr[f][9 + i]     = Tf[9 + i];
            }
        }

        // sequential dependency chain
        int tdv[8];
        {
            const int4* tdq = (const int4*)(tdepArr + rtv * 8);
            int4 a = tdq[0], b = tdq[1];
            tdv[0] = a.x; tdv[1] = a.y; tdv[2] = a.z; tdv[3] = a.w;
            tdv[4] = b.x; tdv[5] = b.y; tdv[6] = b.z; tdv[7] = b.w;
        }
#pragma unroll
        for (int i = 1; i < 8; ++i) {
            float P[12];
            sel8(fr, tdv[i] & 7, P);
            float Y[12];
#pragma unroll
            for (int k = 0; k < 12; ++k) Y[k] = fr[i][k];
#pragma unroll
            for (int r = 0; r < 3; ++r) {
                float a = P[r * 3 + 0], b = P[r * 3 + 1], d = P[r * 3 + 2];
#pragma unroll
                for (int j = 0; j < 3; ++j)
                    fr[i][r * 3 + j] = a * Y[j] + b * Y[3 + j] + d * Y[6 + j];
                fr[i][9 + r] = a * Y[9] + b * Y[10] + d * Y[11] + P[9 + r];
            }
        }

        // write frames to LDS (stride 98 dwords: 8B-aligned, <=2-way conflicts)
        float* fb = lds + L_FR + l * 98;
#pragma unroll
        for (int f = 0; f < 8; ++f) {
#pragma unroll
            for (int j = 0; j < 6; ++j) {
                *(float2*)(fb + f * 12 + 2 * j) =
                    make_float2(fr[f][2 * j], fr[f][2 * j + 1]);
            }
        }
    }
    __syncthreads();

    // ---------------- Phase C: outF + atoms (all 256 threads) --------------
    // outF: frame 0 of each residue, fully coalesced dword stores
#pragma unroll
    for (int k2 = 0; k2 < 3; ++k2) {
        int t2 = tid + 256 * k2;
        if (t2 < cnt * 12) {
            int q = t2 / 12;
            int k = t2 - q * 12;
            outF[(size_t)R0 * 12 + t2] = lds[L_FR + q * 98 + k];
        }
    }

    // atoms: 6 per thread, frame selection = LDS read
#pragma unroll
    for (int kk = 0; kk < 6; ++kk) {
        int ag = tid + 256 * kk;
        if (ag < cnt * 24) {
            int q = ag / 24;
            int a = ag - q * 24;
            int meta = ilds[L_META + q];
            int cmb  = meta & 0xFFFF;
            int rtv  = meta >> 16;
            int f = rdepArr[rtv * 24 + a] & 7;

            const float* fb = lds + L_FR + q * 98 + f * 12;
            float F[12];
#pragma unroll
            for (int j = 0; j < 6; ++j) {
                float2 v = *(const float2*)(fb + 2 * j);
                F[2 * j] = v.x; F[2 * j + 1] = v.y;
            }
            const float* g = rigG + (size_t)cmb * 72 + a * 3;
            float gx = g[0], gy = g[1], gz = g[2];

            float px = fmaf(F[0], gx, fmaf(F[1], gy, fmaf(F[2], gz, F[9])));
            float py = fmaf(F[3], gx, fmaf(F[4], gy, fmaf(F[5], gz, F[10])));
            float pz = fmaf(F[6], gx, fmaf(F[7], gy, fmaf(F[8], gz, F[11])));

            float* o = outR + (size_t)R0 * 72 + (size_t)ag * 3;
            o[0] = px; o[1] = py; o[2] = pz;
        }
    }
}

extern "C" void kernel_launch(void* const* d_in, const int* in_sizes, int n_in,
                              void* d_out, int out_size, void* d_ws, size_t ws_size,
                              hipStream_t stream) {
    const float* o0   = (const float*)d_in[0];
    const float* o1   = (const float*)d_in[1];
    const float* pos  = (const float*)d_in[2];
    const int*   ssA  = (const int*)d_in[3];
    const int*   rtA  = (const int*)d_in[4];
    const float* rigT = (const float*)d_in[5];
    const float* rigG = (const float*)d_in[6];
    const int*   tdep = (const int*)d_in[7];
    const int*   rdep = (const int*)d_in[8];

    const int N = in_sizes[3]; // ss has N elements
    float* outR = (float*)d_out;
    float* outF = (float*)d_out + (size_t)N * 72;

    const int grid = (N + RPB - 1) / RPB;
    model_kernel<<<grid, 256, 0, stream>>>(o0, o1, pos, ssA, rtA, rigT, rigG,
                                           tdep, rdep, outR, outF, N);
}